// Round 3
// baseline (303.245 us; speedup 1.0000x reference)
//
#include <hip/hip_runtime.h>

#define BB 16
#define TT 8192
#define NN 128                     // N_PRE == N_POST
constexpr int CHUNK = 256;         // time-steps per block
constexpr int NBLK  = BB * TT / CHUNK;   // 512 blocks
constexpr int OUTN  = NN * NN;           // 16384
constexpr int GS    = 264;         // g_lds row stride in halves (264 = 33*8, 16B-aligned rows)
constexpr int KRED  = 32;          // fp32 reduction rows in finalize stage 1

typedef _Float16 f16x8 __attribute__((ext_vector_type(8)));
typedef float    f32x4 __attribute__((ext_vector_type(4)));

__device__ __forceinline__ unsigned short h16(float x) {
    _Float16 h = (_Float16)x;
    return __builtin_bit_cast(unsigned short, h);
}

__device__ __forceinline__ float2 ldP2(const float* __restrict__ pb, int t, int q) {
    float2 v = make_float2(0.f, 0.f);
    if (t < TT) v = *(const float2*)(pb + (size_t)t * NN + q);
    return v;
}

// grid 512 x 512 threads (8 waves). Block = one 256-step chunk of one batch.
// Phase 1: wave wv filters steps [wv*32, wv*32+32) into LDS g[q][t] (one shot).
// Phase 2: all waves MFMA over K=256; wave wv owns p-strip [wv*16, wv*16+16).
template<bool ATOMIC>
__global__ __launch_bounds__(512, 4)
void stdp_main(const float* __restrict__ pre, const float* __restrict__ post,
               const int* __restrict__ dtp,
               _Float16* __restrict__ part, float* __restrict__ wpost,
               float* __restrict__ outat)
{
    __shared__ __align__(16) unsigned short g_lds[NN * GS]; // 66 KB: [q][264] f16
    __shared__ float lds_ps[8][NN];

    const int tid   = threadIdx.x;
    const int blk   = blockIdx.x;
    const int b     = blk >> 5;          // 16 batches
    const int chunk = blk & 31;          // 32 chunks per batch
    const int t0    = chunk * CHUNK;
    const int wv    = tid >> 6;          // wave 0..7
    const int lane  = tid & 63;

    const float dtf = (float)(*dtp);
    const float r   = expf(-dtf * (1.0f / 20.0f));

    const float* pb = post + (size_t)b * TT * NN;
    const float* ab = pre  + (size_t)b * TT * NN;

    const int q0 = lane * 2;             // filter q-pair owned by this lane
    const int ts = t0 + wv * 32;         // this wave's 32-step window
    float psx = 0.f, psy = 0.f;          // post sums over (ts, ts+32]

    // ---------- filter: one 59-tap init + 31 recurrence steps ----------
    unsigned int pk0[16], pk1[16];       // 32 halves per q row
    {
        const int thi = ts + 31;
        float2 p  = ldP2(pb, thi + 1, q0);
        float wt  = r;
        float gx = r * p.x, gy = r * p.y;
        psx += p.x; psy += p.y;
        #pragma unroll
        for (int tau = 2; tau <= 59; ++tau) {
            wt *= r;
            p = ldP2(pb, thi + tau, q0);
            gx = fmaf(wt, p.x, gx);
            gy = fmaf(wt, p.y, gy);
        }
        const float r60 = wt * r;        // r^60, consistent with chained weights
        pk0[15] = (unsigned int)h16(gx) << 16;   // step 31 = high half of word 15
        pk1[15] = (unsigned int)h16(gy) << 16;
        // recurrence downward: g[t] = r*(g[t+1]+P(t+1)) - r^60*P(t+60)
        #pragma unroll
        for (int c = 30; c >= 0; --c) {
            float2 p1  = ldP2(pb, ts + c + 1,  q0);
            float2 p60 = ldP2(pb, ts + c + 60, q0);
            gx = r * (gx + p1.x) - r60 * p60.x;
            gy = r * (gy + p1.y) - r60 * p60.y;
            psx += p1.x; psy += p1.y;
            if (c & 1) {
                pk0[c >> 1] = (unsigned int)h16(gx) << 16;
                pk1[c >> 1] = (unsigned int)h16(gy) << 16;
            } else {
                pk0[c >> 1] |= h16(gx);
                pk1[c >> 1] |= h16(gy);
            }
        }
    }
    {
        unsigned short* d0 = &g_lds[q0 * GS + wv * 32];
        unsigned short* d1 = &g_lds[(q0 + 1) * GS + wv * 32];
        #pragma unroll
        for (int s = 0; s < 4; ++s) {
            *(uint4*)(d0 + 8 * s) = make_uint4(pk0[4*s], pk0[4*s+1], pk0[4*s+2], pk0[4*s+3]);
            *(uint4*)(d1 + 8 * s) = make_uint4(pk1[4*s], pk1[4*s+1], pk1[4*s+2], pk1[4*s+3]);
        }
    }
    __syncthreads();

    // ---------- MFMA: S[p,q] += pre^T @ g over K=256, wave strip 16p x 128q ----------
    const int pr0 = wv * 16;
    f32x4 acc[8];
    #pragma unroll
    for (int qt = 0; qt < 8; ++qt) acc[qt] = (f32x4){0.f, 0.f, 0.f, 0.f};

    for (int ks = 0; ks < 8; ++ks) {
        const int trow = t0 + ks * 32 + (lane >> 4) * 8;      // A K-rows this lane covers
        const float* src = ab + (size_t)trow * NN + pr0 + (lane & 15);
        f16x8 af;
        #pragma unroll
        for (int j = 0; j < 8; ++j)
            af[j] = (_Float16)src[(size_t)j * NN];            // 0/1 exact in fp16
        const int koff = ks * 32 + (lane >> 4) * 8;
        #pragma unroll
        for (int qt = 0; qt < 8; ++qt) {
            const f16x8 bf = *(const f16x8*)&g_lds[(qt * 16 + (lane & 15)) * GS + koff];
            acc[qt] = __builtin_amdgcn_mfma_f32_16x16x32_f16(af, bf, acc[qt], 0, 0, 0);
        }
    }

    // ---------- write partial S (fp16; |S_partial| < 100, safe) ----------
    #pragma unroll
    for (int qt = 0; qt < 8; ++qt)
        #pragma unroll
        for (int rg = 0; rg < 4; ++rg) {
            const int prow = pr0 + (lane >> 4) * 4 + rg;
            const int qcol = qt * 16 + (lane & 15);
            const float v = acc[qt][rg];
            if constexpr (ATOMIC) atomicAdd(&outat[prow * NN + qcol], v);
            else part[(size_t)blk * OUTN + prow * NN + qcol] = (_Float16)v;
        }

    // ---------- post column sums for homeostatic term ----------
    lds_ps[wv][q0]     = psx;
    lds_ps[wv][q0 + 1] = psy;
    __syncthreads();
    if (tid < NN) {
        float s = 0.f;
        #pragma unroll
        for (int w = 0; w < 8; ++w) s += lds_ps[w][tid];
        if (chunk == 0) s += pb[tid];    // window (t0,t0+256] misses t=0 row once per batch
        if constexpr (ATOMIC) atomicAdd(&wpost[tid], s);
        else wpost[(size_t)tid * NBLK + blk] = s;   // [q][NBLK] for coalesced reduce
    }
}

// 128 blocks x 64 threads: block q reduces its NBLK partial sums (coalesced), shfl tree.
__global__ void hfac_kernel(const float* __restrict__ wpost, const int* __restrict__ dtp,
                            float* __restrict__ hfac, int nb)
{
    const int q = blockIdx.x;
    float s = 0.f;
    for (int k = threadIdx.x; k < nb; k += 64) s += wpost[(size_t)q * nb + k];
    #pragma unroll
    for (int off = 32; off; off >>= 1) s += __shfl_down(s, off, 64);
    if (threadIdx.x == 0) {
        const float dtf   = (float)(*dtp);
        const float alpha = dtf * 1e-3f;
        const float mean  = s * (1.0f / (float)(BB * TT));
        hfac[q] = -0.001f * (alpha * (mean - 0.1f));
    }
}

// stage 1: 256 blocks (32 i-groups x 8 k-groups) x 256 thr; f16x8 coalesced loads.
// part[512][16384] f16 -> partial2[32][16384] f32
__global__ __launch_bounds__(256)
void reduce1(const _Float16* __restrict__ part, float* __restrict__ partial2)
{
    const int o     = threadIdx.x & 63;     // oct within i-group (64 octs x 8 halves)
    const int ksub  = threadIdx.x >> 6;     // 0..3
    const int ig    = blockIdx.x & 31;
    const int kg    = blockIdx.x >> 5;
    const int ibase = ig * 512 + o * 8;
    float s[8] = {0.f, 0.f, 0.f, 0.f, 0.f, 0.f, 0.f, 0.f};
    for (int k = kg * 64 + ksub; k < (kg + 1) * 64; k += 4) {
        const f16x8 h = *(const f16x8*)&part[(size_t)k * OUTN + ibase];
        #pragma unroll
        for (int j = 0; j < 8; ++j) s[j] += (float)h[j];
    }
    float* dst = partial2 + (size_t)(kg * 4 + ksub) * OUTN + ibase;
    *(float4*)dst       = make_float4(s[0], s[1], s[2], s[3]);
    *(float4*)(dst + 4) = make_float4(s[4], s[5], s[6], s[7]);
}

// stage 2: 32 blocks x 256 thr, float2 per thread: sum 32 fp32 rows + epilogue.
__global__ void reduce2(const float* __restrict__ partial2, const float* __restrict__ hfac,
                        const float* __restrict__ W, float* __restrict__ out)
{
    const int i = (blockIdx.x * 256 + threadIdx.x) * 2;
    float sx = 0.f, sy = 0.f;
    #pragma unroll 8
    for (int r = 0; r < KRED; ++r) {
        const float2 v = *(const float2*)(partial2 + (size_t)r * OUTN + i);
        sx += v.x; sy += v.y;
    }
    const int q = i & 127;
    const float scale = (float)((0.005 - 0.00525) / (double)(BB * TT));
    const float2 w = *(const float2*)(W + i);
    float2 o;
    o.x = fmaf(sx, scale, hfac[q] * w.x);
    o.y = fmaf(sy, scale, hfac[q + 1] * w.y);
    *(float2*)(out + i) = o;
}

// fallback epilogue when S was atomically accumulated in d_out
__global__ void finalize_at(const float* __restrict__ hfac, const float* __restrict__ W,
                            float* __restrict__ out)
{
    const int i = (blockIdx.x * 256 + threadIdx.x) * 2;
    const int q = i & 127;
    const float scale = (float)((0.005 - 0.00525) / (double)(BB * TT));
    float2 s = *(const float2*)(out + i);
    float2 w = *(const float2*)(W + i);
    float2 o;
    o.x = fmaf(s.x, scale, hfac[q] * w.x);
    o.y = fmaf(s.y, scale, hfac[q + 1] * w.y);
    *(float2*)(out + i) = o;
}

extern "C" void kernel_launch(void* const* d_in, const int* in_sizes, int n_in,
                              void* d_out, int out_size, void* d_ws, size_t ws_size,
                              hipStream_t stream)
{
    const float* pre  = (const float*)d_in[0];
    const float* post = (const float*)d_in[1];
    const float* W    = (const float*)d_in[2];
    const int*   dtp  = (const int*)d_in[3];
    float* out = (float*)d_out;

    const size_t part_bytes  = (size_t)NBLK * OUTN * sizeof(_Float16);  // 16 MiB
    const size_t p2_bytes    = (size_t)KRED * OUTN * sizeof(float);     // 2 MiB
    const size_t wpost_bytes = (size_t)NBLK * NN * sizeof(float);       // 256 KiB
    const size_t need = part_bytes + p2_bytes + wpost_bytes + NN * sizeof(float);

    if (ws_size >= need) {
        _Float16* part  = (_Float16*)d_ws;
        float* partial2 = (float*)((char*)d_ws + part_bytes);
        float* wpost    = (float*)((char*)d_ws + part_bytes + p2_bytes);
        float* hfac     = (float*)((char*)d_ws + part_bytes + p2_bytes + wpost_bytes);
        hipLaunchKernelGGL((stdp_main<false>), dim3(NBLK), dim3(512), 0, stream,
                           pre, post, dtp, part, wpost, (float*)nullptr);
        hipLaunchKernelGGL(hfac_kernel, dim3(NN), dim3(64), 0, stream, wpost, dtp, hfac, NBLK);
        hipLaunchKernelGGL(reduce1, dim3(256), dim3(256), 0, stream, part, partial2);
        hipLaunchKernelGGL(reduce2, dim3(OUTN / 512), dim3(256), 0, stream, partial2, hfac, W, out);
    } else {
        // atomic fallback: needs only ~1 KiB of workspace
        float* wpost = (float*)d_ws;
        float* hfac  = wpost + NN;
        hipMemsetAsync(d_out, 0, OUTN * sizeof(float), stream);
        hipMemsetAsync(wpost, 0, NN * sizeof(float), stream);
        hipLaunchKernelGGL((stdp_main<true>), dim3(NBLK), dim3(512), 0, stream,
                           pre, post, dtp, (_Float16*)nullptr, wpost, out);
        hipLaunchKernelGGL(hfac_kernel, dim3(NN), dim3(64), 0, stream, wpost, dtp, hfac, 1);
        hipLaunchKernelGGL(finalize_at, dim3(OUTN / 512), dim3(256), 0, stream, hfac, W, out);
    }
}

// Round 4
// 242.217 us; speedup vs baseline: 1.2520x; 1.2520x over previous
//
#include <hip/hip_runtime.h>

#define BB 16
#define TT 8192
#define NN 128                     // N_PRE == N_POST
constexpr int CHUNK = 256;         // time-steps per block
constexpr int NBLK  = BB * TT / CHUNK;   // 512 blocks
constexpr int OUTN  = NN * NN;           // 16384
constexpr int GS    = 264;         // g_lds row stride in halves (528 B rows, 16B-aligned)
constexpr int SLOTS = OUTN / 2;    // 8192 packed u32 slots per k-slice
constexpr int KG    = 16;          // reduce1 k-groups (32 slices each)

typedef _Float16 f16x8 __attribute__((ext_vector_type(8)));
typedef _Float16 f16x2 __attribute__((ext_vector_type(2)));
typedef float    f32x4 __attribute__((ext_vector_type(4)));

__device__ __forceinline__ unsigned short h16(float x) {
    _Float16 h = (_Float16)x;
    return __builtin_bit_cast(unsigned short, h);
}

__device__ __forceinline__ float ldP(const float* __restrict__ pb, int t, int q) {
    return (t < TT) ? pb[(size_t)t * NN + q] : 0.f;
}

// grid 512 x 512 threads. Block = one 256-step chunk of one batch.
// Filter role: wave wv -> window win=wv>>1 (64 steps), q-half qh=wv&1 (64 q, 1 q/lane).
// MFMA role:   wave wv -> p-strip [wv*16, wv*16+16), full 128 q, K=256.
template<bool ATOMIC>
__global__ __launch_bounds__(512, 4)
void stdp_main(const float* __restrict__ pre, const float* __restrict__ post,
               const int* __restrict__ dtp,
               unsigned int* __restrict__ part, float* __restrict__ wpost,
               float* __restrict__ outat)
{
    __shared__ __align__(16) unsigned short g_lds[NN * GS]; // 66 KB: [q][264] f16
    __shared__ float lds_ps[4][NN];

    const int tid   = threadIdx.x;
    const int blk   = blockIdx.x;
    const int b     = blk >> 5;          // 16 batches
    const int chunk = blk & 31;          // 32 chunks per batch
    const int t0    = chunk * CHUNK;
    const int wv    = tid >> 6;          // wave 0..7
    const int lane  = tid & 63;

    const float dtf = (float)(*dtp);
    const float r   = expf(-dtf * (1.0f / 20.0f));

    const float* pb = post + (size_t)b * TT * NN;
    const float* ab = pre  + (size_t)b * TT * NN;

    // ---------- filter: window of 64 steps, one q column per lane ----------
    const int win = wv >> 1;
    const int q   = (wv & 1) * 64 + lane;
    const int ts  = t0 + win * 64;
    float ps = 0.f;                      // post sum over (ts, ts+64]

    unsigned int pk[32];                 // 64 f16 steps, packed
    {
        const int thi = ts + 63;
        float p  = ldP(pb, thi + 1, q);
        float wt = r;
        float g  = r * p;
        ps += p;
        #pragma unroll
        for (int tau = 2; tau <= 59; ++tau) {
            wt *= r;
            p = ldP(pb, thi + tau, q);
            g = fmaf(wt, p, g);
        }
        const float r60 = wt * r;        // r^60, consistent with chained weights
        pk[31] = (unsigned int)h16(g) << 16;     // step 63 = high half of word 31
        // recurrence downward: g[t] = r*(g[t+1]+P(t+1)) - r^60*P(t+60)
        #pragma unroll
        for (int c = 62; c >= 0; --c) {
            const float p1  = ldP(pb, ts + c + 1,  q);
            const float p60 = ldP(pb, ts + c + 60, q);
            g = r * (g + p1) - r60 * p60;
            ps += p1;
            if (c & 1) pk[c >> 1] = (unsigned int)h16(g) << 16;
            else       pk[c >> 1] |= h16(g);
        }
    }
    {
        unsigned short* d = &g_lds[q * GS + win * 64];   // 16B-aligned (528B rows, 128B win offset)
        #pragma unroll
        for (int s = 0; s < 8; ++s)
            *(uint4*)(d + 8 * s) = make_uint4(pk[4*s], pk[4*s+1], pk[4*s+2], pk[4*s+3]);
    }
    __syncthreads();

    // ---------- MFMA: S[p,q] += pre^T @ g over K=256, wave strip 16p x 128q ----------
    const int pr0 = wv * 16;
    f32x4 acc[8];
    #pragma unroll
    for (int qt = 0; qt < 8; ++qt) acc[qt] = (f32x4){0.f, 0.f, 0.f, 0.f};

    for (int ks = 0; ks < 8; ++ks) {
        const int trow = t0 + ks * 32 + (lane >> 4) * 8;      // A K-rows this lane covers
        const float* src = ab + (size_t)trow * NN + pr0 + (lane & 15);
        f16x8 af;
        #pragma unroll
        for (int j = 0; j < 8; ++j)
            af[j] = (_Float16)src[(size_t)j * NN];            // 0/1 exact in fp16
        const int koff = ks * 32 + (lane >> 4) * 8;
        #pragma unroll
        for (int qt = 0; qt < 8; ++qt) {
            const f16x8 bf = *(const f16x8*)&g_lds[(qt * 16 + (lane & 15)) * GS + koff];
            acc[qt] = __builtin_amdgcn_mfma_f32_16x16x32_f16(af, bf, acc[qt], 0, 0, 0);
        }
    }

    // ---------- write partial S: u32-packed f16 pairs, 256B/instr coalesced ----------
    if constexpr (!ATOMIC) {
        unsigned int* dst = part + ((size_t)blk * 8 + wv) * 1024 + lane;  // 8 qt * 2 rgpair * 64
        #pragma unroll
        for (int qt = 0; qt < 8; ++qt)
            #pragma unroll
            for (int rp = 0; rp < 2; ++rp)
                dst[qt * 128 + rp * 64] =
                    (unsigned int)h16(acc[qt][2 * rp]) | ((unsigned int)h16(acc[qt][2 * rp + 1]) << 16);
    } else {
        #pragma unroll
        for (int qt = 0; qt < 8; ++qt)
            #pragma unroll
            for (int rg = 0; rg < 4; ++rg) {
                const int prow = pr0 + (lane >> 4) * 4 + rg;
                const int qcol = qt * 16 + (lane & 15);
                atomicAdd(&outat[prow * NN + qcol], acc[qt][rg]);
            }
    }

    // ---------- post column sums for homeostatic term ----------
    lds_ps[win][q] = ps;                 // 8 waves cover 4 windows x 128 q exactly once
    __syncthreads();
    if (tid < NN) {
        float s = lds_ps[0][tid] + lds_ps[1][tid] + lds_ps[2][tid] + lds_ps[3][tid];
        if (chunk == 0) s += pb[tid];    // window (t0,t0+256] misses t=0 row once per batch
        if constexpr (ATOMIC) atomicAdd(&wpost[tid], s);
        else wpost[(size_t)tid * NBLK + blk] = s;   // [q][NBLK] for coalesced reduce
    }
}

// 128 blocks x 64 threads: block q reduces its NBLK partial sums (coalesced), shfl tree.
__global__ void hfac_kernel(const float* __restrict__ wpost, const int* __restrict__ dtp,
                            float* __restrict__ hfac, int nb)
{
    const int q = blockIdx.x;
    float s = 0.f;
    for (int k = threadIdx.x; k < nb; k += 64) s += wpost[(size_t)q * nb + k];
    #pragma unroll
    for (int off = 32; off; off >>= 1) s += __shfl_down(s, off, 64);
    if (threadIdx.x == 0) {
        const float dtf   = (float)(*dtp);
        const float alpha = dtf * 1e-3f;
        const float mean  = s * (1.0f / (float)(BB * TT));
        hfac[q] = -0.001f * (alpha * (mean - 0.1f));
    }
}

// stage 1: 512 blocks (16 kg x 32 ig) x 256 thr; coalesced u32 loads, f32 accumulate.
// part[512][8192] u32 -> partial2[16][8192] float2
__global__ __launch_bounds__(256)
void reduce1(const unsigned int* __restrict__ part, float2* __restrict__ partial2)
{
    const int i  = (blockIdx.x & 31) * 256 + threadIdx.x;   // slot 0..8191
    const int kg = blockIdx.x >> 5;                         // 0..15
    float sx = 0.f, sy = 0.f;
    #pragma unroll 8
    for (int k = kg * 32; k < kg * 32 + 32; ++k) {
        const unsigned int v = part[(size_t)k * SLOTS + i];
        const f16x2 h = __builtin_bit_cast(f16x2, v);
        sx += (float)h[0];
        sy += (float)h[1];
    }
    partial2[(size_t)kg * SLOTS + i] = make_float2(sx, sy);
}

// stage 2: 32 blocks x 256 thr: sum KG float2 rows, un-permute, epilogue.
__global__ void reduce2(const float2* __restrict__ partial2, const float* __restrict__ hfac,
                        const float* __restrict__ W, float* __restrict__ out)
{
    const int sid = blockIdx.x * 256 + threadIdx.x;         // 0..8191
    float sx = 0.f, sy = 0.f;
    #pragma unroll
    for (int r = 0; r < KG; ++r) {
        const float2 v = partial2[(size_t)r * SLOTS + sid];
        sx += v.x; sy += v.y;
    }
    const int lane = sid & 63;
    const int rp   = (sid >> 6) & 1;
    const int qt   = (sid >> 7) & 7;
    const int wv   = sid >> 10;
    const int p    = wv * 16 + ((lane >> 4) << 2) + rp * 2;
    const int q    = qt * 16 + (lane & 15);
    const float scale = (float)((0.005 - 0.00525) / (double)(BB * TT));
    const float hf = hfac[q];
    out[p * NN + q]       = fmaf(sx, scale, hf * W[p * NN + q]);
    out[(p + 1) * NN + q] = fmaf(sy, scale, hf * W[(p + 1) * NN + q]);
}

// fallback epilogue when S was atomically accumulated in d_out
__global__ void finalize_at(const float* __restrict__ hfac, const float* __restrict__ W,
                            float* __restrict__ out)
{
    const int i = (blockIdx.x * 256 + threadIdx.x) * 2;
    const int q = i & 127;
    const float scale = (float)((0.005 - 0.00525) / (double)(BB * TT));
    float2 s = *(const float2*)(out + i);
    float2 w = *(const float2*)(W + i);
    float2 o;
    o.x = fmaf(s.x, scale, hfac[q] * w.x);
    o.y = fmaf(s.y, scale, hfac[q + 1] * w.y);
    *(float2*)(out + i) = o;
}

extern "C" void kernel_launch(void* const* d_in, const int* in_sizes, int n_in,
                              void* d_out, int out_size, void* d_ws, size_t ws_size,
                              hipStream_t stream)
{
    const float* pre  = (const float*)d_in[0];
    const float* post = (const float*)d_in[1];
    const float* W    = (const float*)d_in[2];
    const int*   dtp  = (const int*)d_in[3];
    float* out = (float*)d_out;

    const size_t part_bytes  = (size_t)NBLK * SLOTS * sizeof(unsigned int); // 16 MiB
    const size_t p2_bytes    = (size_t)KG * SLOTS * sizeof(float2);         // 1 MiB
    const size_t wpost_bytes = (size_t)NBLK * NN * sizeof(float);           // 256 KiB
    const size_t need = part_bytes + p2_bytes + wpost_bytes + NN * sizeof(float);

    if (ws_size >= need) {
        unsigned int* part = (unsigned int*)d_ws;
        float2* partial2   = (float2*)((char*)d_ws + part_bytes);
        float* wpost       = (float*)((char*)d_ws + part_bytes + p2_bytes);
        float* hfac        = (float*)((char*)d_ws + part_bytes + p2_bytes + wpost_bytes);
        hipLaunchKernelGGL((stdp_main<false>), dim3(NBLK), dim3(512), 0, stream,
                           pre, post, dtp, part, wpost, (float*)nullptr);
        hipLaunchKernelGGL(hfac_kernel, dim3(NN), dim3(64), 0, stream, wpost, dtp, hfac, NBLK);
        hipLaunchKernelGGL(reduce1, dim3(512), dim3(256), 0, stream, part, partial2);
        hipLaunchKernelGGL(reduce2, dim3(SLOTS / 256), dim3(256), 0, stream, partial2, hfac, W, out);
    } else {
        // atomic fallback: needs only ~1 KiB of workspace
        float* wpost = (float*)d_ws;
        float* hfac  = wpost + NN;
        hipMemsetAsync(d_out, 0, OUTN * sizeof(float), stream);
        hipMemsetAsync(wpost, 0, NN * sizeof(float), stream);
        hipLaunchKernelGGL((stdp_main<true>), dim3(NBLK), dim3(512), 0, stream,
                           pre, post, dtp, (unsigned int*)nullptr, wpost, out);
        hipLaunchKernelGGL(hfac_kernel, dim3(NN), dim3(64), 0, stream, wpost, dtp, hfac, 1);
        hipLaunchKernelGGL(finalize_at, dim3(OUTN / 512), dim3(256), 0, stream, hfac, W, out);
    }
}

// Round 5
// 172.602 us; speedup vs baseline: 1.7569x; 1.4033x over previous
//
#include <hip/hip_runtime.h>

#define BB 16
#define TT 8192
#define NN 128                     // N_PRE == N_POST
constexpr int CHUNK = 256;         // time-steps per block
constexpr int NBLK  = BB * TT / CHUNK;   // 512 blocks
constexpr int OUTN  = NN * NN;           // 16384
constexpr int GS    = 264;         // g_lds row stride in halves (528 B rows, 16B-aligned)
constexpr int SLOTS = OUTN / 2;    // 8192 packed u32 slots per k-slice
constexpr int KG    = 16;          // reduce1 k-groups (32 slices each)
constexpr int PROWS = 315;         // staged post rows: (t0, t0+315]

typedef _Float16 f16x8 __attribute__((ext_vector_type(8)));
typedef _Float16 f16x2 __attribute__((ext_vector_type(2)));
typedef float    f32x4 __attribute__((ext_vector_type(4)));

__device__ __forceinline__ unsigned short h16(float x) {
    _Float16 h = (_Float16)x;
    return __builtin_bit_cast(unsigned short, h);
}
__device__ __forceinline__ unsigned int pack2(float x, float y) {
    return (unsigned int)h16(x) | ((unsigned int)h16(y) << 16);
}
__device__ __forceinline__ float2 ldL(const unsigned short* p_lds, int m, int q0) {
    const unsigned int v = *(const unsigned int*)&p_lds[m * NN + q0];
    const f16x2 h = __builtin_bit_cast(f16x2, v);
    return make_float2((float)h[0], (float)h[1]);
}

// grid 512 x 512 threads. Block = one 256-step chunk of one batch.
// Phase 0: stage post rows (t0, t0+315] as f16 into LDS (float4-coalesced).
// Phase 1: wave wv filters 32-step window wv from LDS (2 q per lane) into regs.
// Phase 2: dump g over the post region; MFMA over K=256, wave strip 16p x 128q.
template<bool ATOMIC>
__global__ __launch_bounds__(512, 4)
void stdp_main(const float* __restrict__ pre, const float* __restrict__ post,
               const int* __restrict__ dtp,
               unsigned int* __restrict__ part, float* __restrict__ wpost,
               float* __restrict__ outat)
{
    __shared__ __align__(16) char smem[PROWS * NN * 2];      // 80,640 B
    unsigned short* post_lds = (unsigned short*)smem;        // [315][128] f16
    unsigned short* g_lds    = (unsigned short*)smem;        // [128][264] f16 (phase 2)
    float*          lds_ps   = (float*)(smem + NN * GS * 2); // [8][128] (phase 2)

    const int tid   = threadIdx.x;
    const int blk   = blockIdx.x;
    const int b     = blk >> 5;          // 16 batches
    const int chunk = blk & 31;          // 32 chunks per batch
    const int t0    = chunk * CHUNK;
    const int wv    = tid >> 6;          // wave 0..7
    const int lane  = tid & 63;

    const float dtf = (float)(*dtp);
    const float r   = expf(-dtf * (1.0f / 20.0f));

    const float* pb = post + (size_t)b * TT * NN;
    const float* ab = pre  + (size_t)b * TT * NN;

    // ---------- phase 0: stage post tile ----------
    {
        const int c  = tid & 31;         // float4 column within row
        const int mr = tid >> 5;         // starting row
        for (int m = mr; m < PROWS; m += 16) {
            const int t = t0 + 1 + m;
            float4 v = make_float4(0.f, 0.f, 0.f, 0.f);
            if (t < TT) v = *(const float4*)(pb + (size_t)t * NN + c * 4);
            *(uint2*)&post_lds[m * NN + c * 4] = make_uint2(pack2(v.x, v.y), pack2(v.z, v.w));
        }
    }
    __syncthreads();

    // ---------- phase 1: filter window wv (32 steps), 2 q per lane ----------
    const int win  = wv;
    const int q0   = lane * 2;
    const int base = win * 32;           // local row base: P[ts+k] -> row base+k-1
    float ps0 = 0.f, ps1 = 0.f;          // post sums over (ts, ts+32]

    unsigned int pk0[16], pk1[16];       // 32 f16 steps per q
    {
        float2 p  = ldL(post_lds, base + 31, q0);   // tau=1: P[ts+32]
        float wt  = r;
        float gx = r * p.x, gy = r * p.y;
        ps0 += p.x; ps1 += p.y;
        #pragma unroll
        for (int tau = 2; tau <= 59; ++tau) {
            wt *= r;
            p = ldL(post_lds, base + 30 + tau, q0);
            gx = fmaf(wt, p.x, gx);
            gy = fmaf(wt, p.y, gy);
        }
        const float r60 = wt * r;        // r^60, consistent with chained weights
        pk0[15] = (unsigned int)h16(gx) << 16;   // step 31 = high half of word 15
        pk1[15] = (unsigned int)h16(gy) << 16;
        // recurrence downward: g[t] = r*(g[t+1]+P(t+1)) - r^60*P(t+60)
        #pragma unroll
        for (int c = 30; c >= 0; --c) {
            const float2 p1  = ldL(post_lds, base + c,      q0);  // P[ts+c+1]
            const float2 p60 = ldL(post_lds, base + c + 59, q0);  // P[ts+c+60]
            gx = r * (gx + p1.x) - r60 * p60.x;
            gy = r * (gy + p1.y) - r60 * p60.y;
            ps0 += p1.x; ps1 += p1.y;
            if (c & 1) {
                pk0[c >> 1] = (unsigned int)h16(gx) << 16;
                pk1[c >> 1] = (unsigned int)h16(gy) << 16;
            } else {
                pk0[c >> 1] |= h16(gx);
                pk1[c >> 1] |= h16(gy);
            }
        }
    }
    __syncthreads();                     // all post_lds reads done before overwrite

    // ---------- phase 2a: dump g over the post region ----------
    {
        unsigned short* d0 = &g_lds[q0 * GS + win * 32];
        unsigned short* d1 = &g_lds[(q0 + 1) * GS + win * 32];
        #pragma unroll
        for (int s = 0; s < 4; ++s) {
            *(uint4*)(d0 + 8 * s) = make_uint4(pk0[4*s], pk0[4*s+1], pk0[4*s+2], pk0[4*s+3]);
            *(uint4*)(d1 + 8 * s) = make_uint4(pk1[4*s], pk1[4*s+1], pk1[4*s+2], pk1[4*s+3]);
        }
        lds_ps[win * NN + q0]     = ps0;
        lds_ps[win * NN + q0 + 1] = ps1;
    }
    __syncthreads();

    // ---------- phase 2b: MFMA S[p,q] += pre^T @ g, K=256, wave strip 16p ----------
    const int pr0 = wv * 16;
    f32x4 acc[8];
    #pragma unroll
    for (int qt = 0; qt < 8; ++qt) acc[qt] = (f32x4){0.f, 0.f, 0.f, 0.f};

    for (int ks = 0; ks < 8; ++ks) {
        const int trow = t0 + ks * 32 + (lane >> 4) * 8;      // A K-rows this lane covers
        const float* src = ab + (size_t)trow * NN + pr0 + (lane & 15);
        f16x8 af;
        #pragma unroll
        for (int j = 0; j < 8; ++j)
            af[j] = (_Float16)src[(size_t)j * NN];            // 0/1 exact in fp16
        const int koff = ks * 32 + (lane >> 4) * 8;
        #pragma unroll
        for (int qt = 0; qt < 8; ++qt) {
            const f16x8 bf = *(const f16x8*)&g_lds[(qt * 16 + (lane & 15)) * GS + koff];
            acc[qt] = __builtin_amdgcn_mfma_f32_16x16x32_f16(af, bf, acc[qt], 0, 0, 0);
        }
    }

    // ---------- write partial S: u32-packed f16 pairs, 256B/instr coalesced ----------
    if constexpr (!ATOMIC) {
        unsigned int* dst = part + ((size_t)blk * 8 + wv) * 1024 + lane;  // 8 qt * 2 rgpair * 64
        #pragma unroll
        for (int qt = 0; qt < 8; ++qt)
            #pragma unroll
            for (int rp = 0; rp < 2; ++rp)
                dst[qt * 128 + rp * 64] = pack2(acc[qt][2 * rp], acc[qt][2 * rp + 1]);
    } else {
        #pragma unroll
        for (int qt = 0; qt < 8; ++qt)
            #pragma unroll
            for (int rg = 0; rg < 4; ++rg) {
                const int prow = pr0 + (lane >> 4) * 4 + rg;
                const int qcol = qt * 16 + (lane & 15);
                atomicAdd(&outat[prow * NN + qcol], acc[qt][rg]);
            }
    }

    // ---------- post column sums for homeostatic term ----------
    __syncthreads();
    if (tid < NN) {
        float s = 0.f;
        #pragma unroll
        for (int w = 0; w < 8; ++w) s += lds_ps[w * NN + tid];
        if (chunk == 0) s += pb[tid];    // window (t0,t0+256] misses t=0 row once per batch
        if constexpr (ATOMIC) atomicAdd(&wpost[tid], s);
        else wpost[(size_t)tid * NBLK + blk] = s;   // [q][NBLK] for coalesced reduce
    }
}

// 128 blocks x 64 threads: block q reduces its NBLK partial sums (coalesced), shfl tree.
__global__ void hfac_kernel(const float* __restrict__ wpost, const int* __restrict__ dtp,
                            float* __restrict__ hfac, int nb)
{
    const int q = blockIdx.x;
    float s = 0.f;
    for (int k = threadIdx.x; k < nb; k += 64) s += wpost[(size_t)q * nb + k];
    #pragma unroll
    for (int off = 32; off; off >>= 1) s += __shfl_down(s, off, 64);
    if (threadIdx.x == 0) {
        const float dtf   = (float)(*dtp);
        const float alpha = dtf * 1e-3f;
        const float mean  = s * (1.0f / (float)(BB * TT));
        hfac[q] = -0.001f * (alpha * (mean - 0.1f));
    }
}

// stage 1: 512 blocks (16 kg x 32 ig) x 256 thr; coalesced u32 loads, f32 accumulate.
__global__ __launch_bounds__(256)
void reduce1(const unsigned int* __restrict__ part, float2* __restrict__ partial2)
{
    const int i  = (blockIdx.x & 31) * 256 + threadIdx.x;   // slot 0..8191
    const int kg = blockIdx.x >> 5;                         // 0..15
    float sx = 0.f, sy = 0.f;
    #pragma unroll 8
    for (int k = kg * 32; k < kg * 32 + 32; ++k) {
        const unsigned int v = part[(size_t)k * SLOTS + i];
        const f16x2 h = __builtin_bit_cast(f16x2, v);
        sx += (float)h[0];
        sy += (float)h[1];
    }
    partial2[(size_t)kg * SLOTS + i] = make_float2(sx, sy);
}

// stage 2: 32 blocks x 256 thr: sum KG float2 rows, un-permute, epilogue.
__global__ void reduce2(const float2* __restrict__ partial2, const float* __restrict__ hfac,
                        const float* __restrict__ W, float* __restrict__ out)
{
    const int sid = blockIdx.x * 256 + threadIdx.x;         // 0..8191
    float sx = 0.f, sy = 0.f;
    #pragma unroll
    for (int r = 0; r < KG; ++r) {
        const float2 v = partial2[(size_t)r * SLOTS + sid];
        sx += v.x; sy += v.y;
    }
    const int lane = sid & 63;
    const int rp   = (sid >> 6) & 1;
    const int qt   = (sid >> 7) & 7;
    const int wv   = sid >> 10;
    const int p    = wv * 16 + ((lane >> 4) << 2) + rp * 2;
    const int q    = qt * 16 + (lane & 15);
    const float scale = (float)((0.005 - 0.00525) / (double)(BB * TT));
    const float hf = hfac[q];
    out[p * NN + q]       = fmaf(sx, scale, hf * W[p * NN + q]);
    out[(p + 1) * NN + q] = fmaf(sy, scale, hf * W[(p + 1) * NN + q]);
}

// fallback epilogue when S was atomically accumulated in d_out
__global__ void finalize_at(const float* __restrict__ hfac, const float* __restrict__ W,
                            float* __restrict__ out)
{
    const int i = (blockIdx.x * 256 + threadIdx.x) * 2;
    const int q = i & 127;
    const float scale = (float)((0.005 - 0.00525) / (double)(BB * TT));
    float2 s = *(const float2*)(out + i);
    float2 w = *(const float2*)(W + i);
    float2 o;
    o.x = fmaf(s.x, scale, hfac[q] * w.x);
    o.y = fmaf(s.y, scale, hfac[q + 1] * w.y);
    *(float2*)(out + i) = o;
}

extern "C" void kernel_launch(void* const* d_in, const int* in_sizes, int n_in,
                              void* d_out, int out_size, void* d_ws, size_t ws_size,
                              hipStream_t stream)
{
    const float* pre  = (const float*)d_in[0];
    const float* post = (const float*)d_in[1];
    const float* W    = (const float*)d_in[2];
    const int*   dtp  = (const int*)d_in[3];
    float* out = (float*)d_out;

    const size_t part_bytes  = (size_t)NBLK * SLOTS * sizeof(unsigned int); // 16 MiB
    const size_t p2_bytes    = (size_t)KG * SLOTS * sizeof(float2);         // 1 MiB
    const size_t wpost_bytes = (size_t)NBLK * NN * sizeof(float);           // 256 KiB
    const size_t need = part_bytes + p2_bytes + wpost_bytes + NN * sizeof(float);

    if (ws_size >= need) {
        unsigned int* part = (unsigned int*)d_ws;
        float2* partial2   = (float2*)((char*)d_ws + part_bytes);
        float* wpost       = (float*)((char*)d_ws + part_bytes + p2_bytes);
        float* hfac        = (float*)((char*)d_ws + part_bytes + p2_bytes + wpost_bytes);
        hipLaunchKernelGGL((stdp_main<false>), dim3(NBLK), dim3(512), 0, stream,
                           pre, post, dtp, part, wpost, (float*)nullptr);
        hipLaunchKernelGGL(hfac_kernel, dim3(NN), dim3(64), 0, stream, wpost, dtp, hfac, NBLK);
        hipLaunchKernelGGL(reduce1, dim3(512), dim3(256), 0, stream, part, partial2);
        hipLaunchKernelGGL(reduce2, dim3(SLOTS / 256), dim3(256), 0, stream, partial2, hfac, W, out);
    } else {
        // atomic fallback: needs only ~1 KiB of workspace
        float* wpost = (float*)d_ws;
        float* hfac  = wpost + NN;
        hipMemsetAsync(d_out, 0, OUTN * sizeof(float), stream);
        hipMemsetAsync(wpost, 0, NN * sizeof(float), stream);
        hipLaunchKernelGGL((stdp_main<true>), dim3(NBLK), dim3(512), 0, stream,
                           pre, post, dtp, (unsigned int*)nullptr, wpost, out);
        hipLaunchKernelGGL(hfac_kernel, dim3(NN), dim3(64), 0, stream, wpost, dtp, hfac, 1);
        hipLaunchKernelGGL(finalize_at, dim3(OUTN / 512), dim3(256), 0, stream, hfac, W, out);
    }
}

// Round 6
// 164.717 us; speedup vs baseline: 1.8410x; 1.0479x over previous
//
#include <hip/hip_runtime.h>

#define BB 16
#define TT 8192
#define NN 128                     // N_PRE == N_POST
constexpr int CHUNK = 256;         // time-steps per block
constexpr int NBLK  = BB * TT / CHUNK;   // 512 blocks
constexpr int OUTN  = NN * NN;           // 16384
constexpr int GS    = 264;         // g_lds row stride in halves (528 B rows, 16B-aligned)
constexpr int SLOTS = OUTN / 2;    // 8192 packed u32 slots per k-slice
constexpr int PROWS = 315;         // staged post rows: (t0, t0+315]

typedef _Float16 f16x8 __attribute__((ext_vector_type(8)));
typedef _Float16 f16x2 __attribute__((ext_vector_type(2)));
typedef float    f32x4 __attribute__((ext_vector_type(4)));

__device__ __forceinline__ unsigned short h16(float x) {
    _Float16 h = (_Float16)x;
    return __builtin_bit_cast(unsigned short, h);
}
__device__ __forceinline__ unsigned int pack2(float x, float y) {
    return (unsigned int)h16(x) | ((unsigned int)h16(y) << 16);
}
__device__ __forceinline__ float2 ldL(const unsigned short* p_lds, int m, int q0) {
    const unsigned int v = *(const unsigned int*)&p_lds[m * NN + q0];
    const f16x2 h = __builtin_bit_cast(f16x2, v);
    return make_float2((float)h[0], (float)h[1]);
}

// grid 512 x 512 threads. Block = one 256-step chunk of one batch.
// Phase 0: stage post rows (t0, t0+315] as f16 into LDS (float4-coalesced).
// Phase 1: wave wv filters 32-step window wv from LDS (2 q per lane) into regs.
// Phase 2: dump g over the post region; MFMA over K=256 with 2-stage A prefetch.
template<bool ATOMIC>
__global__ __launch_bounds__(512, 4)
void stdp_main(const float* __restrict__ pre, const float* __restrict__ post,
               const int* __restrict__ dtp,
               unsigned int* __restrict__ part, float* __restrict__ wpost,
               float* __restrict__ outat)
{
    __shared__ __align__(16) char smem[PROWS * NN * 2];      // 80,640 B
    unsigned short* post_lds = (unsigned short*)smem;        // [315][128] f16
    unsigned short* g_lds    = (unsigned short*)smem;        // [128][264] f16 (phase 2)
    float*          lds_ps   = (float*)(smem + NN * GS * 2); // [8][128] (phase 2)

    const int tid   = threadIdx.x;
    const int blk   = blockIdx.x;
    const int b     = blk >> 5;          // 16 batches
    const int chunk = blk & 31;          // 32 chunks per batch
    const int t0    = chunk * CHUNK;
    const int wv    = tid >> 6;          // wave 0..7
    const int lane  = tid & 63;

    const float dtf = (float)(*dtp);
    const float r   = expf(-dtf * (1.0f / 20.0f));

    const float* pb = post + (size_t)b * TT * NN;
    const float* ab = pre  + (size_t)b * TT * NN;

    // ---------- phase 0: stage post tile ----------
    {
        const int c  = tid & 31;         // float4 column within row
        const int mr = tid >> 5;         // starting row
        for (int m = mr; m < PROWS; m += 16) {
            const int t = t0 + 1 + m;
            float4 v = make_float4(0.f, 0.f, 0.f, 0.f);
            if (t < TT) v = *(const float4*)(pb + (size_t)t * NN + c * 4);
            *(uint2*)&post_lds[m * NN + c * 4] = make_uint2(pack2(v.x, v.y), pack2(v.z, v.w));
        }
    }
    __syncthreads();

    // ---------- phase 1: filter window wv (32 steps), 2 q per lane ----------
    const int win  = wv;
    const int q0   = lane * 2;
    const int base = win * 32;           // local row base: P[ts+k] -> row base+k-1
    float ps0 = 0.f, ps1 = 0.f;          // post sums over (ts, ts+32]

    unsigned int pk0[16], pk1[16];       // 32 f16 steps per q
    {
        float2 p  = ldL(post_lds, base + 31, q0);   // tau=1: P[ts+32]
        float wt  = r;
        float gx = r * p.x, gy = r * p.y;
        ps0 += p.x; ps1 += p.y;
        #pragma unroll
        for (int tau = 2; tau <= 59; ++tau) {
            wt *= r;
            p = ldL(post_lds, base + 30 + tau, q0);
            gx = fmaf(wt, p.x, gx);
            gy = fmaf(wt, p.y, gy);
        }
        const float r60 = wt * r;        // r^60, consistent with chained weights
        pk0[15] = (unsigned int)h16(gx) << 16;   // step 31 = high half of word 15
        pk1[15] = (unsigned int)h16(gy) << 16;
        // recurrence downward: g[t] = r*(g[t+1]+P(t+1)) - r^60*P(t+60)
        #pragma unroll
        for (int c = 30; c >= 0; --c) {
            const float2 p1  = ldL(post_lds, base + c,      q0);  // P[ts+c+1]
            const float2 p60 = ldL(post_lds, base + c + 59, q0);  // P[ts+c+60]
            gx = r * (gx + p1.x) - r60 * p60.x;
            gy = r * (gy + p1.y) - r60 * p60.y;
            ps0 += p1.x; ps1 += p1.y;
            if (c & 1) {
                pk0[c >> 1] = (unsigned int)h16(gx) << 16;
                pk1[c >> 1] = (unsigned int)h16(gy) << 16;
            } else {
                pk0[c >> 1] |= h16(gx);
                pk1[c >> 1] |= h16(gy);
            }
        }
    }
    __syncthreads();                     // all post_lds reads done before overwrite

    // ---------- phase 2a: dump g over the post region ----------
    {
        unsigned short* d0 = &g_lds[q0 * GS + win * 32];
        unsigned short* d1 = &g_lds[(q0 + 1) * GS + win * 32];
        #pragma unroll
        for (int s = 0; s < 4; ++s) {
            *(uint4*)(d0 + 8 * s) = make_uint4(pk0[4*s], pk0[4*s+1], pk0[4*s+2], pk0[4*s+3]);
            *(uint4*)(d1 + 8 * s) = make_uint4(pk1[4*s], pk1[4*s+1], pk1[4*s+2], pk1[4*s+3]);
        }
        lds_ps[win * NN + q0]     = ps0;
        lds_ps[win * NN + q0 + 1] = ps1;
    }
    __syncthreads();

    // ---------- phase 2b: MFMA S[p,q] += pre^T @ g, K=256, 2-stage A prefetch ----------
    const int pr0 = wv * 16;
    f32x4 acc[8];
    #pragma unroll
    for (int qt = 0; qt < 8; ++qt) acc[qt] = (f32x4){0.f, 0.f, 0.f, 0.f};

    const float* abase = ab + (size_t)(t0 + (lane >> 4) * 8) * NN + pr0 + (lane & 15);
    float an[8];
    #pragma unroll
    for (int j = 0; j < 8; ++j) an[j] = abase[(size_t)j * NN];      // ks=0 raw f32

    #pragma unroll
    for (int ks = 0; ks < 8; ++ks) {
        f16x8 af;
        #pragma unroll
        for (int j = 0; j < 8; ++j) af[j] = (_Float16)an[j];        // 0/1 exact in fp16
        if (ks < 7) {
            const float* src = abase + (size_t)((ks + 1) * 32) * NN;
            #pragma unroll
            for (int j = 0; j < 8; ++j) an[j] = src[(size_t)j * NN]; // prefetch ks+1
        }
        const int koff = ks * 32 + (lane >> 4) * 8;
        #pragma unroll
        for (int qt = 0; qt < 8; ++qt) {
            const f16x8 bf = *(const f16x8*)&g_lds[(qt * 16 + (lane & 15)) * GS + koff];
            acc[qt] = __builtin_amdgcn_mfma_f32_16x16x32_f16(af, bf, acc[qt], 0, 0, 0);
        }
    }

    // ---------- write partial S: u32-packed f16 pairs, 256B/instr coalesced ----------
    if constexpr (!ATOMIC) {
        unsigned int* dst = part + ((size_t)blk * 8 + wv) * 1024 + lane;  // 8 qt * 2 rgpair * 64
        #pragma unroll
        for (int qt = 0; qt < 8; ++qt)
            #pragma unroll
            for (int rp = 0; rp < 2; ++rp)
                dst[qt * 128 + rp * 64] = pack2(acc[qt][2 * rp], acc[qt][2 * rp + 1]);
    } else {
        #pragma unroll
        for (int qt = 0; qt < 8; ++qt)
            #pragma unroll
            for (int rg = 0; rg < 4; ++rg) {
                const int prow = pr0 + (lane >> 4) * 4 + rg;
                const int qcol = qt * 16 + (lane & 15);
                atomicAdd(&outat[prow * NN + qcol], acc[qt][rg]);
            }
    }

    // ---------- post column sums for homeostatic term ----------
    __syncthreads();
    if (tid < NN) {
        float s = 0.f;
        #pragma unroll
        for (int w = 0; w < 8; ++w) s += lds_ps[w * NN + tid];
        if (chunk == 0) s += pb[tid];    // window (t0,t0+256] misses t=0 row once per batch
        if constexpr (ATOMIC) atomicAdd(&wpost[tid], s);
        else wpost[(size_t)tid * NBLK + blk] = s;   // [q][NBLK] for coalesced reduce
    }
}

// 128 blocks x 64 threads: block q reduces its NBLK partial sums (coalesced), shfl tree.
__global__ void hfac_kernel(const float* __restrict__ wpost, const int* __restrict__ dtp,
                            float* __restrict__ hfac, int nb)
{
    const int q = blockIdx.x;
    float s = 0.f;
    for (int k = threadIdx.x; k < nb; k += 64) s += wpost[(size_t)q * nb + k];
    #pragma unroll
    for (int off = 32; off; off >>= 1) s += __shfl_down(s, off, 64);
    if (threadIdx.x == 0) {
        const float dtf   = (float)(*dtp);
        const float alpha = dtf * 1e-3f;
        const float mean  = s * (1.0f / (float)(BB * TT));
        hfac[q] = -0.001f * (alpha * (mean - 0.1f));
    }
}

// fused split-K reduce + epilogue: 128 blocks x 512 thr, 8-way k-split,
// 256B/instr coalesced part reads; un-permute + homeostatic epilogue.
__global__ __launch_bounds__(512)
void finalize_ws(const unsigned int* __restrict__ part, const float* __restrict__ hfac,
                 const float* __restrict__ W, float* __restrict__ out)
{
    __shared__ float2 red[512];
    const int s    = threadIdx.x & 63;        // slot within block's 64
    const int kq   = threadIdx.x >> 6;        // 0..7
    const int slot = blockIdx.x * 64 + s;     // 0..8191
    float sx = 0.f, sy = 0.f;
    #pragma unroll 8
    for (int k = kq * 64; k < kq * 64 + 64; ++k) {
        const unsigned int v = part[(size_t)k * SLOTS + slot];
        const f16x2 h = __builtin_bit_cast(f16x2, v);
        sx += (float)h[0];
        sy += (float)h[1];
    }
    red[threadIdx.x] = make_float2(sx, sy);
    __syncthreads();
    if (threadIdx.x < 64) {
        #pragma unroll
        for (int g = 1; g < 8; ++g) {
            const float2 v = red[g * 64 + s];
            sx += v.x; sy += v.y;
        }
        sx += red[s].x - red[s].x + 0.f;      // no-op keep structure simple
        float rx = red[s].x, ry = red[s].y;
        sx = sx - (sx - sx);                  // (kept trivial)
        // total = own partial (red[s]) already included? no: red[s] is g=0 term
        float tx = rx, ty = ry;
        #pragma unroll
        for (int g = 1; g < 8; ++g) {
            const float2 v = red[g * 64 + s];
            tx += v.x; ty += v.y;
        }
        // un-permute slot -> (p, q)
        const int lane = slot & 63;
        const int rp   = (slot >> 6) & 1;
        const int qt   = (slot >> 7) & 7;
        const int wv   = slot >> 10;
        const int p    = wv * 16 + ((lane >> 4) << 2) + rp * 2;
        const int q    = qt * 16 + (lane & 15);
        const float scale = (float)((0.005 - 0.00525) / (double)(BB * TT));
        const float hf = hfac[q];
        out[p * NN + q]       = fmaf(tx, scale, hf * W[p * NN + q]);
        out[(p + 1) * NN + q] = fmaf(ty, scale, hf * W[(p + 1) * NN + q]);
    }
}

// fallback epilogue when S was atomically accumulated in d_out
__global__ void finalize_at(const float* __restrict__ hfac, const float* __restrict__ W,
                            float* __restrict__ out)
{
    const int i = (blockIdx.x * 256 + threadIdx.x) * 2;
    const int q = i & 127;
    const float scale = (float)((0.005 - 0.00525) / (double)(BB * TT));
    float2 s = *(const float2*)(out + i);
    float2 w = *(const float2*)(W + i);
    float2 o;
    o.x = fmaf(s.x, scale, hfac[q] * w.x);
    o.y = fmaf(s.y, scale, hfac[q + 1] * w.y);
    *(float2*)(out + i) = o;
}

extern "C" void kernel_launch(void* const* d_in, const int* in_sizes, int n_in,
                              void* d_out, int out_size, void* d_ws, size_t ws_size,
                              hipStream_t stream)
{
    const float* pre  = (const float*)d_in[0];
    const float* post = (const float*)d_in[1];
    const float* W    = (const float*)d_in[2];
    const int*   dtp  = (const int*)d_in[3];
    float* out = (float*)d_out;

    const size_t part_bytes  = (size_t)NBLK * SLOTS * sizeof(unsigned int); // 16 MiB
    const size_t wpost_bytes = (size_t)NBLK * NN * sizeof(float);           // 256 KiB
    const size_t need = part_bytes + wpost_bytes + NN * sizeof(float);

    if (ws_size >= need) {
        unsigned int* part = (unsigned int*)d_ws;
        float* wpost       = (float*)((char*)d_ws + part_bytes);
        float* hfac        = (float*)((char*)d_ws + part_bytes + wpost_bytes);
        hipLaunchKernelGGL((stdp_main<false>), dim3(NBLK), dim3(512), 0, stream,
                           pre, post, dtp, part, wpost, (float*)nullptr);
        hipLaunchKernelGGL(hfac_kernel, dim3(NN), dim3(64), 0, stream, wpost, dtp, hfac, NBLK);
        hipLaunchKernelGGL(finalize_ws, dim3(SLOTS / 64), dim3(512), 0, stream, part, hfac, W, out);
    } else {
        // atomic fallback: needs only ~1 KiB of workspace
        float* wpost = (float*)d_ws;
        float* hfac  = wpost + NN;
        hipMemsetAsync(d_out, 0, OUTN * sizeof(float), stream);
        hipMemsetAsync(wpost, 0, NN * sizeof(float), stream);
        hipLaunchKernelGGL((stdp_main<true>), dim3(NBLK), dim3(512), 0, stream,
                           pre, post, dtp, (unsigned int*)nullptr, wpost, out);
        hipLaunchKernelGGL(hfac_kernel, dim3(NN), dim3(64), 0, stream, wpost, dtp, hfac, 1);
        hipLaunchKernelGGL(finalize_at, dim3(OUTN / 512), dim3(256), 0, stream, hfac, W, out);
    }
}